// Round 9
// baseline (762.699 us; speedup 1.0000x reference)
//
#include <hip/hip_runtime.h>

#define N_USERS 100000
#define N_ITEMS 50000
#define N_NODES 150000
#define DIM 32
#define N_EDGES 8000000
#define B_OUT 65536

#define NB 1024                      // row buckets
#define RPB 147                      // rows per bucket (1024*147 >= 150000)
#define CH 16384                     // edges per chunk (payload fits LDS)
#define N_PBLK ((N_EDGES + CH - 1) / CH)   // 489
#define PART_T 1024
#define EPT (CH / PART_T)            // 16 edges per thread
#define MS_T 512
#define T 256
#define NRED 8
#define RS_LD (NB + 1)               // runstart leading dim: [chunk][NB+1]
#define COLSPLIT 75008               // low slice: 75008 cols * 64B = 4.8 MB

__device__ __forceinline__ unsigned short f2bf(float f) {
    unsigned b = __float_as_uint(f);
    return (unsigned short)((b + 0x7FFFu + ((b >> 16) & 1u)) >> 16);   // RNE
}
__device__ __forceinline__ float bf2f(unsigned short u) {
    return __uint_as_float((unsigned)u << 16);
}

// ---------------------------------------------------------------------------
// init: x_a(bf16) = concat(user_emb, item_emb); emb_sum(f32) = same.
// ---------------------------------------------------------------------------
__global__ void init_kernel(const float* __restrict__ user_emb,
                            const float* __restrict__ item_emb,
                            unsigned short* __restrict__ x_a,
                            float* __restrict__ emb_sum) {
    int i = blockIdx.x * blockDim.x + threadIdx.x;   // float4 index
    const int total = N_NODES * DIM / 4;
    if (i >= total) return;
    const int user_f4 = N_USERS * DIM / 4;
    float4 v;
    if (i < user_f4) v = ((const float4*)user_emb)[i];
    else             v = ((const float4*)item_emb)[i - user_f4];
    ((float4*)emb_sum)[i] = v;
    ushort4 h;
    h.x = f2bf(v.x); h.y = f2bf(v.y); h.z = f2bf(v.z); h.w = f2bf(v.w);
    ((ushort4*)x_a)[i] = h;
}

// ---------------------------------------------------------------------------
// Partition (proven R8): LDS histogram -> shuffle scan -> rank into LDS
// payload -> coalesced stream-out. Payload: int2{ (row_local<<18)|col, val }.
// ---------------------------------------------------------------------------
__global__ void __launch_bounds__(PART_T)
part_kernel(const int* __restrict__ rows,
            const int* __restrict__ cols,
            const float* __restrict__ vals,
            int* __restrict__ runstart,
            int2* __restrict__ bucket_ev) {
    __shared__ int2 buf[CH];         // 128 KB staged payload
    __shared__ int hist[NB];         // 4 KB
    __shared__ int wsum[16];
    const int tid   = threadIdx.x;
    const int chunk = blockIdx.x;
    const int e0    = chunk * CH;
    const int ecnt  = (N_EDGES - e0 < CH) ? (N_EDGES - e0) : CH;
    const int lane  = tid & 63, wid = tid >> 6;

    hist[tid] = 0;
    __syncthreads();

    int myrow[EPT];
    #pragma unroll
    for (int j = 0; j < EPT; ++j) {
        int idx = j * PART_T + tid;
        int r = (idx < ecnt) ? rows[e0 + idx] : -1;
        myrow[j] = r;
        if (r >= 0) atomicAdd(&hist[(unsigned)r / RPB], 1);
    }
    __syncthreads();

    int v = hist[tid];
    int inc = v;
    #pragma unroll
    for (int off = 1; off < 64; off <<= 1) {
        int t = __shfl_up(inc, off, 64);
        if (lane >= off) inc += t;
    }
    if (lane == 63) wsum[wid] = inc;
    __syncthreads();
    if (wid == 0) {
        int s = (lane < 16) ? wsum[lane] : 0;
        #pragma unroll
        for (int off = 1; off < 16; off <<= 1) {
            int t = __shfl_up(s, off, 64);
            if (lane >= off) s += t;
        }
        if (lane < 16) wsum[lane] = s;
    }
    __syncthreads();
    int base = (wid > 0) ? wsum[wid - 1] : 0;
    int incl = base + inc;
    int excl = incl - v;
    runstart[(size_t)chunk * RS_LD + tid] = e0 + excl;
    if (tid == NB - 1) runstart[(size_t)chunk * RS_LD + NB] = e0 + incl;
    hist[tid] = excl;
    __syncthreads();

    #pragma unroll
    for (int j = 0; j < EPT; ++j) {
        int r = myrow[j];
        if (r < 0) continue;
        int idx = j * PART_T + tid;
        unsigned b = (unsigned)r / RPB;
        int k = atomicAdd(&hist[b], 1);
        int2 ev;
        ev.x = (int)(((unsigned)(r - (int)b * RPB) << 18) | (unsigned)cols[e0 + idx]);
        ev.y = __float_as_int(vals[e0 + idx]);
        buf[k] = ev;
    }
    __syncthreads();

    const int n4 = ecnt >> 1;
    const int4* b4 = (const int4*)buf;
    int4* g4 = (int4*)(bucket_ev + e0);
    for (int i = tid; i < n4; i += PART_T) g4[i] = b4[i];
}

// ---------------------------------------------------------------------------
// Bucket totals + scan -> bcsr. (unchanged, totals independent of col split)
// ---------------------------------------------------------------------------
__global__ void btot_kernel(const int* __restrict__ runstart, int* __restrict__ partial) {
    const int b = threadIdx.x;
    const int g = blockIdx.x;
    int c = 0;
    for (int ch = g; ch < N_PBLK; ch += NRED)
        c += runstart[(size_t)ch * RS_LD + b + 1] - runstart[(size_t)ch * RS_LD + b];
    partial[g * NB + b] = c;
}

__global__ void bscan_kernel(const int* __restrict__ partial,
                             int* __restrict__ bcsr,
                             int* __restrict__ row_ptr) {
    __shared__ int wsum[16];
    const int tid = threadIdx.x;
    const int lane = tid & 63, wid = tid >> 6;
    int v = 0;
    #pragma unroll
    for (int g = 0; g < NRED; ++g) v += partial[g * NB + tid];
    int inc = v;
    #pragma unroll
    for (int off = 1; off < 64; off <<= 1) {
        int t = __shfl_up(inc, off, 64);
        if (lane >= off) inc += t;
    }
    if (lane == 63) wsum[wid] = inc;
    __syncthreads();
    if (wid == 0) {
        int s = (lane < 16) ? wsum[lane] : 0;
        #pragma unroll
        for (int off = 1; off < 16; off <<= 1) {
            int t = __shfl_up(s, off, 64);
            if (lane >= off) s += t;
        }
        if (lane < 16) wsum[lane] = s;
    }
    __syncthreads();
    int base = (wid > 0) ? wsum[wid - 1] : 0;
    bcsr[tid] = base + inc - v;          // exclusive
    if (tid == 0) row_ptr[N_NODES] = N_EDGES;
}

// ---------------------------------------------------------------------------
// Mini-scatter: one block per bucket. Counts (row, col-half) pairs over the
// bucket's runs, shuffle scan over 2*RPB bins -> row_ptr + mid + LDS cursors,
// then scatter -> CSR where each row's edges are [lo-cols][hi-cols].
// ---------------------------------------------------------------------------
__global__ void __launch_bounds__(MS_T)
mini_scatter_kernel(const int* __restrict__ runstart,
                    const int2* __restrict__ bucket_ev,
                    const int* __restrict__ bcsr,
                    int* __restrict__ row_ptr,
                    int* __restrict__ mid,
                    int2* __restrict__ csr_ev) {
    __shared__ int rs0[N_PBLK];
    __shared__ int rs1[N_PBLK];
    __shared__ int cnt2[RPB * 2];    // 294: (row_local, col_half)
    __shared__ int cur2[RPB * 2];
    __shared__ int wsum[MS_T / 64];
    const int b   = blockIdx.x;
    const int tid = threadIdx.x;
    const int lane = tid & 63, wid = tid >> 6;

    for (int i = tid; i < N_PBLK; i += MS_T) {
        rs0[i] = runstart[(size_t)i * RS_LD + b];
        rs1[i] = runstart[(size_t)i * RS_LD + b + 1];
    }
    if (tid < RPB * 2) cnt2[tid] = 0;
    __syncthreads();

    const int grp = tid >> 4, ln = tid & 15;     // 16-lane groups
    for (int c = grp; c < N_PBLK; c += (MS_T / 16))
        for (int i = rs0[c] + ln; i < rs1[c]; i += 16) {
            unsigned key = (unsigned)bucket_ev[i].x;
            int rl  = (int)(key >> 18);
            int col = (int)(key & 0x3FFFFu);
            atomicAdd(&cnt2[rl * 2 + (col >= COLSPLIT)], 1);
        }
    __syncthreads();

    int v = (tid < RPB * 2) ? cnt2[tid] : 0;
    int inc = v;
    #pragma unroll
    for (int off = 1; off < 64; off <<= 1) {
        int t = __shfl_up(inc, off, 64);
        if (lane >= off) inc += t;
    }
    if (lane == 63) wsum[wid] = inc;
    __syncthreads();
    if (wid == 0) {
        int s = (lane < MS_T / 64) ? wsum[lane] : 0;
        #pragma unroll
        for (int off = 1; off < MS_T / 64; off <<= 1) {
            int t = __shfl_up(s, off, 64);
            if (lane >= off) s += t;
        }
        if (lane < MS_T / 64) wsum[lane] = s;
    }
    __syncthreads();
    const int cb = bcsr[b];
    if (tid < RPB * 2) {
        int base = (wid > 0) ? wsum[wid - 1] : 0;
        int excl = cb + base + inc - v;
        cur2[tid] = excl;
        int r = b * RPB + (tid >> 1);
        if (r < N_NODES) {
            if ((tid & 1) == 0) row_ptr[r] = excl;
            else                mid[r]     = excl;
        }
    }
    __syncthreads();

    for (int c = grp; c < N_PBLK; c += (MS_T / 16))
        for (int i = rs0[c] + ln; i < rs1[c]; i += 16) {
            int2 ev = bucket_ev[i];
            unsigned key = (unsigned)ev.x;
            int rl  = (int)(key >> 18);
            int col = (int)(key & 0x3FFFFu);
            int pos = atomicAdd(&cur2[rl * 2 + (col >= COLSPLIT)], 1);
            int2 o; o.x = col; o.y = ev.y;
            csr_ev[pos] = o;
        }
}

// ---------------------------------------------------------------------------
// SpMM pass A (cols < COLSPLIT): partial acc -> accbuf (f32, nt store).
// Half-wave per row, lane = dim. csr loads nontemporal (protect xin in L2).
// ---------------------------------------------------------------------------
__global__ void spmmA_kernel(const int* __restrict__ seg_s,
                             const int* __restrict__ seg_e,
                             const long long* __restrict__ csr,
                             const unsigned short* __restrict__ xin,
                             float* __restrict__ accbuf) {
    int tid = blockIdx.x * blockDim.x + threadIdx.x;
    int row = tid >> 5;
    int d   = tid & 31;
    if (row >= N_NODES) return;
    int s = seg_s[row];
    int e = seg_e[row];
    float acc = 0.f;
    int i = s;
    for (; i + 8 <= e; i += 8) {
        long long p[8];
        #pragma unroll
        for (int j = 0; j < 8; ++j) p[j] = __builtin_nontemporal_load(csr + i + j);
        float x[8];
        #pragma unroll
        for (int j = 0; j < 8; ++j)
            x[j] = bf2f(xin[(unsigned)p[j] * DIM + d]);
        #pragma unroll
        for (int j = 0; j < 8; ++j)
            acc += __int_as_float((int)(p[j] >> 32)) * x[j];
    }
    for (; i < e; ++i) {
        long long p = __builtin_nontemporal_load(csr + i);
        acc += __int_as_float((int)(p >> 32)) * bf2f(xin[(unsigned)p * DIM + d]);
    }
    __builtin_nontemporal_store(acc, &accbuf[row * DIM + d]);
}

// ---------------------------------------------------------------------------
// SpMM pass B (cols >= COLSPLIT): acc = accbuf + remaining edges;
// emb_sum += acc; xout(bf16) unless last layer.
// ---------------------------------------------------------------------------
__global__ void spmmB_kernel(const int* __restrict__ seg_s,
                             const int* __restrict__ seg_e,
                             const long long* __restrict__ csr,
                             const unsigned short* __restrict__ xin,
                             const float* __restrict__ accbuf,
                             unsigned short* __restrict__ xout,
                             float* __restrict__ emb_sum,
                             int write_x) {
    int tid = blockIdx.x * blockDim.x + threadIdx.x;
    int row = tid >> 5;
    int d   = tid & 31;
    if (row >= N_NODES) return;
    int s = seg_s[row];
    int e = seg_e[row];
    int o = row * DIM + d;
    float acc = __builtin_nontemporal_load(&accbuf[o]);
    int i = s;
    for (; i + 8 <= e; i += 8) {
        long long p[8];
        #pragma unroll
        for (int j = 0; j < 8; ++j) p[j] = __builtin_nontemporal_load(csr + i + j);
        float x[8];
        #pragma unroll
        for (int j = 0; j < 8; ++j)
            x[j] = bf2f(xin[(unsigned)p[j] * DIM + d]);
        #pragma unroll
        for (int j = 0; j < 8; ++j)
            acc += __int_as_float((int)(p[j] >> 32)) * x[j];
    }
    for (; i < e; ++i) {
        long long p = __builtin_nontemporal_load(csr + i);
        acc += __int_as_float((int)(p >> 32)) * bf2f(xin[(unsigned)p * DIM + d]);
    }
    emb_sum[o] += acc;
    if (write_x) xout[o] = f2bf(acc);
}

// ---------------------------------------------------------------------------
// Readout.
// ---------------------------------------------------------------------------
__global__ void final_kernel(const int* __restrict__ users,
                             const int* __restrict__ items,
                             const float* __restrict__ emb_sum,
                             const float* __restrict__ means,
                             const float* __restrict__ stds,
                             float* __restrict__ out) {
    int b = blockIdx.x * blockDim.x + threadIdx.x;
    if (b >= B_OUT) return;
    int u  = users[b];
    int it = items[b] + N_USERS;
    const float4* su = (const float4*)(emb_sum + (size_t)u  * DIM);
    const float4* si = (const float4*)(emb_sum + (size_t)it * DIM);
    float gamma = 0.f;
    #pragma unroll
    for (int k = 0; k < DIM / 4; ++k) {
        float4 a = su[k], c = si[k];
        gamma += (a.x * 0.25f) * (c.x * 0.25f) + (a.y * 0.25f) * (c.y * 0.25f)
               + (a.z * 0.25f) * (c.z * 0.25f) + (a.w * 0.25f) * (c.w * 0.25f);
    }
    out[b] = gamma * stds[u] + means[u];
}

extern "C" void kernel_launch(void* const* d_in, const int* in_sizes, int n_in,
                              void* d_out, int out_size, void* d_ws, size_t ws_size,
                              hipStream_t stream) {
    const int*   users    = (const int*)d_in[0];
    const int*   items    = (const int*)d_in[1];
    const int*   rows     = (const int*)d_in[2];
    const int*   cols     = (const int*)d_in[3];
    const float* vals     = (const float*)d_in[4];
    const float* user_emb = (const float*)d_in[5];
    const float* item_emb = (const float*)d_in[6];
    const float* means    = (const float*)d_in[7];
    const float* stds     = (const float*)d_in[8];
    float* out = (float*)d_out;

    char* w = (char*)d_ws;
    size_t off = 0;
    auto alloc = [&](size_t bytes) -> void* {
        void* p = w + off;
        off = (off + bytes + 255) & ~(size_t)255;
        return p;
    };
    // Region A: bucket_ev (live: part -> mini_scatter) aliases
    //           {x_a, x_b, emb_sum, accf} (live: init -> end).
    size_t regionA = ((size_t)N_PBLK * CH * sizeof(int2) + 255) & ~(size_t)255;  // 64.1 MB
    char* a0 = (char*)alloc(regionA);
    int2* bucket_ev = (int2*)a0;
    size_t aoff = 0;
    auto allocA = [&](size_t bytes) -> void* {
        void* p = a0 + aoff;
        aoff = (aoff + bytes + 255) & ~(size_t)255;
        return p;
    };
    unsigned short* x_a     = (unsigned short*)allocA((size_t)N_NODES * DIM * 2);  // 9.6 MB
    unsigned short* x_b     = (unsigned short*)allocA((size_t)N_NODES * DIM * 2);  // 9.6 MB
    float*          emb_sum = (float*)allocA((size_t)N_NODES * DIM * 4);           // 19.2 MB
    float*          accf    = (float*)allocA((size_t)N_NODES * DIM * 4);           // 19.2 MB (57.6 <= 64.1)

    int*  runstart = (int*) alloc((size_t)N_PBLK * RS_LD * sizeof(int));       // 2.0 MB
    int*  partial  = (int*) alloc((size_t)NRED * NB * sizeof(int));
    int*  row_ptr  = (int*) alloc((size_t)(N_NODES + 1) * sizeof(int));
    int*  mid      = (int*) alloc((size_t)N_NODES * sizeof(int));
    int*  bcsr     = (int*) alloc((size_t)NB * sizeof(int));
    int2* csr_ev   = (int2*)alloc((size_t)N_EDGES * sizeof(int2));              // 64 MB
    const long long* csr = (const long long*)csr_ev;
    (void)ws_size;

    const int g_init  = (N_NODES * DIM / 4 + T - 1) / T;
    const int g_spmm  = (N_NODES * DIM + T - 1) / T;     // 18750
    const int g_final = (B_OUT + T - 1) / T;

    // --- CSR build (col-segmented per row) ---
    part_kernel<<<N_PBLK, PART_T, 0, stream>>>(rows, cols, vals, runstart, bucket_ev);
    btot_kernel<<<NRED, NB, 0, stream>>>(runstart, partial);
    bscan_kernel<<<1, NB, 0, stream>>>(partial, bcsr, row_ptr);
    mini_scatter_kernel<<<NB, MS_T, 0, stream>>>(runstart, bucket_ev, bcsr, row_ptr, mid, csr_ev);

    // --- dense pipeline (bucket_ev dead from here; region reused) ---
    init_kernel<<<g_init, T, 0, stream>>>(user_emb, item_emb, x_a, emb_sum);

    // layer 1: x_b = A x_a
    spmmA_kernel<<<g_spmm, T, 0, stream>>>(row_ptr, mid, csr, x_a, accf);
    spmmB_kernel<<<g_spmm, T, 0, stream>>>(mid, row_ptr + 1, csr, x_a, accf, x_b, emb_sum, 1);
    // layer 2: x_a = A x_b
    spmmA_kernel<<<g_spmm, T, 0, stream>>>(row_ptr, mid, csr, x_b, accf);
    spmmB_kernel<<<g_spmm, T, 0, stream>>>(mid, row_ptr + 1, csr, x_b, accf, x_a, emb_sum, 1);
    // layer 3: emb_sum += A x_a (no x store)
    spmmA_kernel<<<g_spmm, T, 0, stream>>>(row_ptr, mid, csr, x_a, accf);
    spmmB_kernel<<<g_spmm, T, 0, stream>>>(mid, row_ptr + 1, csr, x_a, accf, nullptr, emb_sum, 0);

    final_kernel<<<g_final, T, 0, stream>>>(users, items, emb_sum, means, stds, out);
}

// Round 10
// 572.871 us; speedup vs baseline: 1.3314x; 1.3314x over previous
//
#include <hip/hip_runtime.h>

#define N_USERS 100000
#define N_ITEMS 50000
#define N_NODES 150000
#define DIM 32
#define N_EDGES 8000000
#define B_OUT 65536

#define NB 1024                      // row buckets
#define RPB 147                      // rows per bucket (1024*147 >= 150000)
#define CH 16384                     // edges per chunk (payload fits LDS)
#define N_PBLK ((N_EDGES + CH - 1) / CH)   // 489
#define PART_T 1024
#define EPT (CH / PART_T)            // 16 edges per thread
#define MS_T 512
#define T 256
#define NRED 8
#define RS_LD (NB + 1)               // runstart leading dim: [chunk][NB+1]

__device__ __forceinline__ unsigned short f2bf(float f) {
    unsigned b = __float_as_uint(f);
    return (unsigned short)((b + 0x7FFFu + ((b >> 16) & 1u)) >> 16);   // RNE
}
__device__ __forceinline__ float bf2f(unsigned short u) {
    return __uint_as_float((unsigned)u << 16);
}

// ---------------------------------------------------------------------------
// init: x_a(bf16) = concat(user_emb, item_emb); emb_sum(f32) = same.
// ---------------------------------------------------------------------------
__global__ void init_kernel(const float* __restrict__ user_emb,
                            const float* __restrict__ item_emb,
                            unsigned short* __restrict__ x_a,
                            float* __restrict__ emb_sum) {
    int i = blockIdx.x * blockDim.x + threadIdx.x;   // float4 index
    const int total = N_NODES * DIM / 4;
    if (i >= total) return;
    const int user_f4 = N_USERS * DIM / 4;
    float4 v;
    if (i < user_f4) v = ((const float4*)user_emb)[i];
    else             v = ((const float4*)item_emb)[i - user_f4];
    ((float4*)emb_sum)[i] = v;
    ushort4 h;
    h.x = f2bf(v.x); h.y = f2bf(v.y); h.z = f2bf(v.z); h.w = f2bf(v.w);
    ((ushort4*)x_a)[i] = h;
}

// ---------------------------------------------------------------------------
// Partition (proven R8): LDS histogram -> shuffle scan -> rank into LDS
// payload -> coalesced stream-out. Payload: int2{ (row_local<<18)|col, val }.
// ---------------------------------------------------------------------------
__global__ void __launch_bounds__(PART_T)
part_kernel(const int* __restrict__ rows,
            const int* __restrict__ cols,
            const float* __restrict__ vals,
            int* __restrict__ runstart,
            int2* __restrict__ bucket_ev) {
    __shared__ int2 buf[CH];         // 128 KB staged payload
    __shared__ int hist[NB];         // 4 KB
    __shared__ int wsum[16];
    const int tid   = threadIdx.x;
    const int chunk = blockIdx.x;
    const int e0    = chunk * CH;
    const int ecnt  = (N_EDGES - e0 < CH) ? (N_EDGES - e0) : CH;
    const int lane  = tid & 63, wid = tid >> 6;

    hist[tid] = 0;
    __syncthreads();

    int myrow[EPT];
    #pragma unroll
    for (int j = 0; j < EPT; ++j) {
        int idx = j * PART_T + tid;
        int r = (idx < ecnt) ? rows[e0 + idx] : -1;
        myrow[j] = r;
        if (r >= 0) atomicAdd(&hist[(unsigned)r / RPB], 1);
    }
    __syncthreads();

    int v = hist[tid];
    int inc = v;
    #pragma unroll
    for (int off = 1; off < 64; off <<= 1) {
        int t = __shfl_up(inc, off, 64);
        if (lane >= off) inc += t;
    }
    if (lane == 63) wsum[wid] = inc;
    __syncthreads();
    if (wid == 0) {
        int s = (lane < 16) ? wsum[lane] : 0;
        #pragma unroll
        for (int off = 1; off < 16; off <<= 1) {
            int t = __shfl_up(s, off, 64);
            if (lane >= off) s += t;
        }
        if (lane < 16) wsum[lane] = s;
    }
    __syncthreads();
    int base = (wid > 0) ? wsum[wid - 1] : 0;
    int incl = base + inc;
    int excl = incl - v;
    runstart[(size_t)chunk * RS_LD + tid] = e0 + excl;
    if (tid == NB - 1) runstart[(size_t)chunk * RS_LD + NB] = e0 + incl;
    hist[tid] = excl;
    __syncthreads();

    #pragma unroll
    for (int j = 0; j < EPT; ++j) {
        int r = myrow[j];
        if (r < 0) continue;
        int idx = j * PART_T + tid;
        unsigned b = (unsigned)r / RPB;
        int k = atomicAdd(&hist[b], 1);
        int2 ev;
        ev.x = (int)(((unsigned)(r - (int)b * RPB) << 18) | (unsigned)cols[e0 + idx]);
        ev.y = __float_as_int(vals[e0 + idx]);
        buf[k] = ev;
    }
    __syncthreads();

    const int n4 = ecnt >> 1;
    const int4* b4 = (const int4*)buf;
    int4* g4 = (int4*)(bucket_ev + e0);
    for (int i = tid; i < n4; i += PART_T) g4[i] = b4[i];
}

// ---------------------------------------------------------------------------
// Bucket totals + scan -> bcsr.
// ---------------------------------------------------------------------------
__global__ void btot_kernel(const int* __restrict__ runstart, int* __restrict__ partial) {
    const int b = threadIdx.x;
    const int g = blockIdx.x;
    int c = 0;
    for (int ch = g; ch < N_PBLK; ch += NRED)
        c += runstart[(size_t)ch * RS_LD + b + 1] - runstart[(size_t)ch * RS_LD + b];
    partial[g * NB + b] = c;
}

__global__ void bscan_kernel(const int* __restrict__ partial,
                             int* __restrict__ bcsr,
                             int* __restrict__ row_ptr) {
    __shared__ int wsum[16];
    const int tid = threadIdx.x;
    const int lane = tid & 63, wid = tid >> 6;
    int v = 0;
    #pragma unroll
    for (int g = 0; g < NRED; ++g) v += partial[g * NB + tid];
    int inc = v;
    #pragma unroll
    for (int off = 1; off < 64; off <<= 1) {
        int t = __shfl_up(inc, off, 64);
        if (lane >= off) inc += t;
    }
    if (lane == 63) wsum[wid] = inc;
    __syncthreads();
    if (wid == 0) {
        int s = (lane < 16) ? wsum[lane] : 0;
        #pragma unroll
        for (int off = 1; off < 16; off <<= 1) {
            int t = __shfl_up(s, off, 64);
            if (lane >= off) s += t;
        }
        if (lane < 16) wsum[lane] = s;
    }
    __syncthreads();
    int base = (wid > 0) ? wsum[wid - 1] : 0;
    bcsr[tid] = base + inc - v;          // exclusive
    if (tid == 0) row_ptr[N_NODES] = N_EDGES;
}

// ---------------------------------------------------------------------------
// Mini-scatter (proven R8): one block per bucket, 16-lane groups.
// ---------------------------------------------------------------------------
__global__ void __launch_bounds__(MS_T)
mini_scatter_kernel(const int* __restrict__ runstart,
                    const int2* __restrict__ bucket_ev,
                    const int* __restrict__ bcsr,
                    int* __restrict__ row_ptr,
                    int2* __restrict__ csr_ev) {
    __shared__ int rs0[N_PBLK];
    __shared__ int rs1[N_PBLK];
    __shared__ int cnt_r[RPB];
    __shared__ int cur[RPB];
    __shared__ int wsum[MS_T / 64];
    const int b   = blockIdx.x;
    const int tid = threadIdx.x;
    const int lane = tid & 63, wid = tid >> 6;

    for (int i = tid; i < N_PBLK; i += MS_T) {
        rs0[i] = runstart[(size_t)i * RS_LD + b];
        rs1[i] = runstart[(size_t)i * RS_LD + b + 1];
    }
    if (tid < RPB) cnt_r[tid] = 0;
    __syncthreads();

    const int grp = tid >> 4, ln = tid & 15;     // 16-lane groups
    for (int c = grp; c < N_PBLK; c += (MS_T / 16))
        for (int i = rs0[c] + ln; i < rs1[c]; i += 16)
            atomicAdd(&cnt_r[(unsigned)bucket_ev[i].x >> 18], 1);
    __syncthreads();

    int v = (tid < RPB) ? cnt_r[tid] : 0;
    int inc = v;
    #pragma unroll
    for (int off = 1; off < 64; off <<= 1) {
        int t = __shfl_up(inc, off, 64);
        if (lane >= off) inc += t;
    }
    if (lane == 63) wsum[wid] = inc;
    __syncthreads();
    if (wid == 0) {
        int s = (lane < MS_T / 64) ? wsum[lane] : 0;
        #pragma unroll
        for (int off = 1; off < MS_T / 64; off <<= 1) {
            int t = __shfl_up(s, off, 64);
            if (lane >= off) s += t;
        }
        if (lane < MS_T / 64) wsum[lane] = s;
    }
    __syncthreads();
    const int cb = bcsr[b];
    if (tid < RPB) {
        int base = (wid > 0) ? wsum[wid - 1] : 0;
        int excl = cb + base + inc - v;
        cur[tid] = excl;
        int r = b * RPB + tid;
        if (r < N_NODES) row_ptr[r] = excl;
    }
    __syncthreads();

    for (int c = grp; c < N_PBLK; c += (MS_T / 16))
        for (int i = rs0[c] + ln; i < rs1[c]; i += 16) {
            int2 ev = bucket_ev[i];
            unsigned key = (unsigned)ev.x;
            int pos = atomicAdd(&cur[key >> 18], 1);
            int2 o; o.x = (int)(key & 0x3FFFFu); o.y = ev.y;
            csr_ev[pos] = o;
        }
}

// ---------------------------------------------------------------------------
// CSR SpMM, bf16 gather, f32 accumulate. Half-wave per row, lane = dim.
// 16-deep unroll: 16 outstanding gathers per half-wave (latency hiding).
// csr loads nontemporal (read-once stream; don't thrash xin in cache).
// Fused: emb_sum += acc; xout(bf16) stored unless last layer.
// ---------------------------------------------------------------------------
__global__ void spmm_kernel(const int* __restrict__ row_ptr,
                            const long long* __restrict__ csr,
                            const unsigned short* __restrict__ xin,
                            unsigned short* __restrict__ xout,
                            float* __restrict__ emb_sum,
                            int write_x) {
    int tid = blockIdx.x * blockDim.x + threadIdx.x;
    int row = tid >> 5;
    int d   = tid & 31;
    if (row >= N_NODES) return;
    int s = row_ptr[row];
    int e = row_ptr[row + 1];
    float acc = 0.f;
    int i = s;
    for (; i + 16 <= e; i += 16) {
        long long p[16];
        #pragma unroll
        for (int j = 0; j < 16; ++j) p[j] = __builtin_nontemporal_load(csr + i + j);
        float x[16];
        #pragma unroll
        for (int j = 0; j < 16; ++j)
            x[j] = bf2f(xin[(unsigned)p[j] * DIM + d]);
        #pragma unroll
        for (int j = 0; j < 16; ++j)
            acc += __int_as_float((int)(p[j] >> 32)) * x[j];
    }
    for (; i + 4 <= e; i += 4) {
        long long p[4];
        #pragma unroll
        for (int j = 0; j < 4; ++j) p[j] = __builtin_nontemporal_load(csr + i + j);
        float x[4];
        #pragma unroll
        for (int j = 0; j < 4; ++j)
            x[j] = bf2f(xin[(unsigned)p[j] * DIM + d]);
        #pragma unroll
        for (int j = 0; j < 4; ++j)
            acc += __int_as_float((int)(p[j] >> 32)) * x[j];
    }
    for (; i < e; ++i) {
        long long p = __builtin_nontemporal_load(csr + i);
        acc += __int_as_float((int)(p >> 32)) * bf2f(xin[(unsigned)p * DIM + d]);
    }
    int o = row * DIM + d;
    if (write_x) xout[o] = f2bf(acc);
    emb_sum[o] += acc;
}

// ---------------------------------------------------------------------------
// Readout.
// ---------------------------------------------------------------------------
__global__ void final_kernel(const int* __restrict__ users,
                             const int* __restrict__ items,
                             const float* __restrict__ emb_sum,
                             const float* __restrict__ means,
                             const float* __restrict__ stds,
                             float* __restrict__ out) {
    int b = blockIdx.x * blockDim.x + threadIdx.x;
    if (b >= B_OUT) return;
    int u  = users[b];
    int it = items[b] + N_USERS;
    const float4* su = (const float4*)(emb_sum + (size_t)u  * DIM);
    const float4* si = (const float4*)(emb_sum + (size_t)it * DIM);
    float gamma = 0.f;
    #pragma unroll
    for (int k = 0; k < DIM / 4; ++k) {
        float4 a = su[k], c = si[k];
        gamma += (a.x * 0.25f) * (c.x * 0.25f) + (a.y * 0.25f) * (c.y * 0.25f)
               + (a.z * 0.25f) * (c.z * 0.25f) + (a.w * 0.25f) * (c.w * 0.25f);
    }
    out[b] = gamma * stds[u] + means[u];
}

extern "C" void kernel_launch(void* const* d_in, const int* in_sizes, int n_in,
                              void* d_out, int out_size, void* d_ws, size_t ws_size,
                              hipStream_t stream) {
    const int*   users    = (const int*)d_in[0];
    const int*   items    = (const int*)d_in[1];
    const int*   rows     = (const int*)d_in[2];
    const int*   cols     = (const int*)d_in[3];
    const float* vals     = (const float*)d_in[4];
    const float* user_emb = (const float*)d_in[5];
    const float* item_emb = (const float*)d_in[6];
    const float* means    = (const float*)d_in[7];
    const float* stds     = (const float*)d_in[8];
    float* out = (float*)d_out;

    char* w = (char*)d_ws;
    size_t off = 0;
    auto alloc = [&](size_t bytes) -> void* {
        void* p = w + off;
        off = (off + bytes + 255) & ~(size_t)255;
        return p;
    };
    // Region A: bucket_ev (live: part -> mini_scatter) aliases
    //           {x_a, x_b, emb_sum} (live: init -> end).
    size_t regionA = ((size_t)N_PBLK * CH * sizeof(int2) + 255) & ~(size_t)255;  // 64.1 MB
    char* a0 = (char*)alloc(regionA);
    int2* bucket_ev = (int2*)a0;
    size_t aoff = 0;
    auto allocA = [&](size_t bytes) -> void* {
        void* p = a0 + aoff;
        aoff = (aoff + bytes + 255) & ~(size_t)255;
        return p;
    };
    unsigned short* x_a     = (unsigned short*)allocA((size_t)N_NODES * DIM * 2);  // 9.6 MB
    unsigned short* x_b     = (unsigned short*)allocA((size_t)N_NODES * DIM * 2);  // 9.6 MB
    float*          emb_sum = (float*)allocA((size_t)N_NODES * DIM * 4);           // 19.2 MB

    int*  runstart = (int*) alloc((size_t)N_PBLK * RS_LD * sizeof(int));       // 2.0 MB
    int*  partial  = (int*) alloc((size_t)NRED * NB * sizeof(int));
    int*  row_ptr  = (int*) alloc((size_t)(N_NODES + 1) * sizeof(int));
    int*  bcsr     = (int*) alloc((size_t)NB * sizeof(int));
    int2* csr_ev   = (int2*)alloc((size_t)N_EDGES * sizeof(int2));              // 64 MB
    const long long* csr = (const long long*)csr_ev;
    (void)ws_size;

    const int g_init  = (N_NODES * DIM / 4 + T - 1) / T;
    const int g_spmm  = (N_NODES * DIM + T - 1) / T;     // 18750
    const int g_final = (B_OUT + T - 1) / T;

    // --- CSR build ---
    part_kernel<<<N_PBLK, PART_T, 0, stream>>>(rows, cols, vals, runstart, bucket_ev);
    btot_kernel<<<NRED, NB, 0, stream>>>(runstart, partial);
    bscan_kernel<<<1, NB, 0, stream>>>(partial, bcsr, row_ptr);
    mini_scatter_kernel<<<NB, MS_T, 0, stream>>>(runstart, bucket_ev, bcsr, row_ptr, csr_ev);

    // --- dense pipeline (bucket_ev dead from here; region reused) ---
    init_kernel<<<g_init, T, 0, stream>>>(user_emb, item_emb, x_a, emb_sum);
    spmm_kernel<<<g_spmm, T, 0, stream>>>(row_ptr, csr, x_a, x_b, emb_sum, 1);
    spmm_kernel<<<g_spmm, T, 0, stream>>>(row_ptr, csr, x_b, x_a, emb_sum, 1);
    spmm_kernel<<<g_spmm, T, 0, stream>>>(row_ptr, csr, x_a, x_b, emb_sum, 0);

    final_kernel<<<g_final, T, 0, stream>>>(users, items, emb_sum, means, stds, out);
}

// Round 11
// 447.327 us; speedup vs baseline: 1.7050x; 1.2807x over previous
//
#include <hip/hip_runtime.h>

#define N_USERS 100000
#define N_ITEMS 50000
#define N_NODES 150000
#define DIM 32
#define N_EDGES 8000000
#define B_OUT 65536

#define NB 1024                      // row buckets
#define RPB 147                      // rows per bucket (1024*147 >= 150000)
#define CH 16384                     // edges per chunk (payload fits LDS)
#define N_PBLK ((N_EDGES + CH - 1) / CH)   // 489
#define PART_T 1024
#define EPT (CH / PART_T)            // 16 edges per thread
#define MS_T 512
#define T 256
#define NRED 8
#define RS_LD (NB + 1)               // runstart leading dim: [chunk][NB+1]

__device__ __forceinline__ unsigned short f2bf(float f) {
    unsigned b = __float_as_uint(f);
    return (unsigned short)((b + 0x7FFFu + ((b >> 16) & 1u)) >> 16);   // RNE
}
__device__ __forceinline__ float bf2f(unsigned short u) {
    return __uint_as_float((unsigned)u << 16);
}
__device__ __forceinline__ float bflo(unsigned u) {
    return __uint_as_float(u << 16);
}
__device__ __forceinline__ float bfhi(unsigned u) {
    return __uint_as_float(u & 0xFFFF0000u);
}

// ---------------------------------------------------------------------------
// init: x_a(bf16) = concat(user_emb, item_emb); emb_sum(f32) = same.
// ---------------------------------------------------------------------------
__global__ void init_kernel(const float* __restrict__ user_emb,
                            const float* __restrict__ item_emb,
                            unsigned short* __restrict__ x_a,
                            float* __restrict__ emb_sum) {
    int i = blockIdx.x * blockDim.x + threadIdx.x;   // float4 index
    const int total = N_NODES * DIM / 4;
    if (i >= total) return;
    const int user_f4 = N_USERS * DIM / 4;
    float4 v;
    if (i < user_f4) v = ((const float4*)user_emb)[i];
    else             v = ((const float4*)item_emb)[i - user_f4];
    ((float4*)emb_sum)[i] = v;
    ushort4 h;
    h.x = f2bf(v.x); h.y = f2bf(v.y); h.z = f2bf(v.z); h.w = f2bf(v.w);
    ((ushort4*)x_a)[i] = h;
}

// ---------------------------------------------------------------------------
// Partition (proven R8): LDS histogram -> shuffle scan -> rank into LDS
// payload -> coalesced stream-out. Payload: int2{ (row_local<<18)|col, val }.
// ---------------------------------------------------------------------------
__global__ void __launch_bounds__(PART_T)
part_kernel(const int* __restrict__ rows,
            const int* __restrict__ cols,
            const float* __restrict__ vals,
            int* __restrict__ runstart,
            int2* __restrict__ bucket_ev) {
    __shared__ int2 buf[CH];         // 128 KB staged payload
    __shared__ int hist[NB];         // 4 KB
    __shared__ int wsum[16];
    const int tid   = threadIdx.x;
    const int chunk = blockIdx.x;
    const int e0    = chunk * CH;
    const int ecnt  = (N_EDGES - e0 < CH) ? (N_EDGES - e0) : CH;
    const int lane  = tid & 63, wid = tid >> 6;

    hist[tid] = 0;
    __syncthreads();

    int myrow[EPT];
    #pragma unroll
    for (int j = 0; j < EPT; ++j) {
        int idx = j * PART_T + tid;
        int r = (idx < ecnt) ? rows[e0 + idx] : -1;
        myrow[j] = r;
        if (r >= 0) atomicAdd(&hist[(unsigned)r / RPB], 1);
    }
    __syncthreads();

    int v = hist[tid];
    int inc = v;
    #pragma unroll
    for (int off = 1; off < 64; off <<= 1) {
        int t = __shfl_up(inc, off, 64);
        if (lane >= off) inc += t;
    }
    if (lane == 63) wsum[wid] = inc;
    __syncthreads();
    if (wid == 0) {
        int s = (lane < 16) ? wsum[lane] : 0;
        #pragma unroll
        for (int off = 1; off < 16; off <<= 1) {
            int t = __shfl_up(s, off, 64);
            if (lane >= off) s += t;
        }
        if (lane < 16) wsum[lane] = s;
    }
    __syncthreads();
    int base = (wid > 0) ? wsum[wid - 1] : 0;
    int incl = base + inc;
    int excl = incl - v;
    runstart[(size_t)chunk * RS_LD + tid] = e0 + excl;
    if (tid == NB - 1) runstart[(size_t)chunk * RS_LD + NB] = e0 + incl;
    hist[tid] = excl;
    __syncthreads();

    #pragma unroll
    for (int j = 0; j < EPT; ++j) {
        int r = myrow[j];
        if (r < 0) continue;
        int idx = j * PART_T + tid;
        unsigned b = (unsigned)r / RPB;
        int k = atomicAdd(&hist[b], 1);
        int2 ev;
        ev.x = (int)(((unsigned)(r - (int)b * RPB) << 18) | (unsigned)cols[e0 + idx]);
        ev.y = __float_as_int(vals[e0 + idx]);
        buf[k] = ev;
    }
    __syncthreads();

    const int n4 = ecnt >> 1;
    const int4* b4 = (const int4*)buf;
    int4* g4 = (int4*)(bucket_ev + e0);
    for (int i = tid; i < n4; i += PART_T) g4[i] = b4[i];
}

// ---------------------------------------------------------------------------
// Bucket totals + scan -> bcsr.
// ---------------------------------------------------------------------------
__global__ void btot_kernel(const int* __restrict__ runstart, int* __restrict__ partial) {
    const int b = threadIdx.x;
    const int g = blockIdx.x;
    int c = 0;
    for (int ch = g; ch < N_PBLK; ch += NRED)
        c += runstart[(size_t)ch * RS_LD + b + 1] - runstart[(size_t)ch * RS_LD + b];
    partial[g * NB + b] = c;
}

__global__ void bscan_kernel(const int* __restrict__ partial,
                             int* __restrict__ bcsr,
                             int* __restrict__ row_ptr) {
    __shared__ int wsum[16];
    const int tid = threadIdx.x;
    const int lane = tid & 63, wid = tid >> 6;
    int v = 0;
    #pragma unroll
    for (int g = 0; g < NRED; ++g) v += partial[g * NB + tid];
    int inc = v;
    #pragma unroll
    for (int off = 1; off < 64; off <<= 1) {
        int t = __shfl_up(inc, off, 64);
        if (lane >= off) inc += t;
    }
    if (lane == 63) wsum[wid] = inc;
    __syncthreads();
    if (wid == 0) {
        int s = (lane < 16) ? wsum[lane] : 0;
        #pragma unroll
        for (int off = 1; off < 16; off <<= 1) {
            int t = __shfl_up(s, off, 64);
            if (lane >= off) s += t;
        }
        if (lane < 16) wsum[lane] = s;
    }
    __syncthreads();
    int base = (wid > 0) ? wsum[wid - 1] : 0;
    bcsr[tid] = base + inc - v;          // exclusive
    if (tid == 0) row_ptr[N_NODES] = N_EDGES;
}

// ---------------------------------------------------------------------------
// Mini-scatter (proven R8): one block per bucket, 16-lane groups.
// ---------------------------------------------------------------------------
__global__ void __launch_bounds__(MS_T)
mini_scatter_kernel(const int* __restrict__ runstart,
                    const int2* __restrict__ bucket_ev,
                    const int* __restrict__ bcsr,
                    int* __restrict__ row_ptr,
                    int2* __restrict__ csr_ev) {
    __shared__ int rs0[N_PBLK];
    __shared__ int rs1[N_PBLK];
    __shared__ int cnt_r[RPB];
    __shared__ int cur[RPB];
    __shared__ int wsum[MS_T / 64];
    const int b   = blockIdx.x;
    const int tid = threadIdx.x;
    const int lane = tid & 63, wid = tid >> 6;

    for (int i = tid; i < N_PBLK; i += MS_T) {
        rs0[i] = runstart[(size_t)i * RS_LD + b];
        rs1[i] = runstart[(size_t)i * RS_LD + b + 1];
    }
    if (tid < RPB) cnt_r[tid] = 0;
    __syncthreads();

    const int grp = tid >> 4, ln = tid & 15;     // 16-lane groups
    for (int c = grp; c < N_PBLK; c += (MS_T / 16))
        for (int i = rs0[c] + ln; i < rs1[c]; i += 16)
            atomicAdd(&cnt_r[(unsigned)bucket_ev[i].x >> 18], 1);
    __syncthreads();

    int v = (tid < RPB) ? cnt_r[tid] : 0;
    int inc = v;
    #pragma unroll
    for (int off = 1; off < 64; off <<= 1) {
        int t = __shfl_up(inc, off, 64);
        if (lane >= off) inc += t;
    }
    if (lane == 63) wsum[wid] = inc;
    __syncthreads();
    if (wid == 0) {
        int s = (lane < MS_T / 64) ? wsum[lane] : 0;
        #pragma unroll
        for (int off = 1; off < MS_T / 64; off <<= 1) {
            int t = __shfl_up(s, off, 64);
            if (lane >= off) s += t;
        }
        if (lane < MS_T / 64) wsum[lane] = s;
    }
    __syncthreads();
    const int cb = bcsr[b];
    if (tid < RPB) {
        int base = (wid > 0) ? wsum[wid - 1] : 0;
        int excl = cb + base + inc - v;
        cur[tid] = excl;
        int r = b * RPB + tid;
        if (r < N_NODES) row_ptr[r] = excl;
    }
    __syncthreads();

    for (int c = grp; c < N_PBLK; c += (MS_T / 16))
        for (int i = rs0[c] + ln; i < rs1[c]; i += 16) {
            int2 ev = bucket_ev[i];
            unsigned key = (unsigned)ev.x;
            int pos = atomicAdd(&cur[key >> 18], 1);
            int2 o; o.x = (int)(key & 0x3FFFFu); o.y = ev.y;
            csr_ev[pos] = o;
        }
}

// ---------------------------------------------------------------------------
// CSR SpMM, 16B-granular bf16 gather, f32 accumulate.
// Half-wave per row; lane = (edge-slot j = 0..7, seg = 0..3).
// Per iteration the half-wave covers 16 edges (2 batches of 8); each lane
// issues one uint4 gather (8 dims) per batch -> 4 lane-addresses per edge
// instead of 32 (TA address-throughput was the R8 bottleneck).
// Row tail masked by w=0 (gathers row 0 harmlessly). Butterfly shfl_xor
// (4,8,16) allreduces edge-slots; j==0 lanes write 16B.
// ---------------------------------------------------------------------------
__global__ void spmm_kernel(const int* __restrict__ row_ptr,
                            const long long* __restrict__ csr,
                            const unsigned short* __restrict__ xin,
                            unsigned short* __restrict__ xout,
                            float* __restrict__ emb_sum,
                            int write_x) {
    int tid = blockIdx.x * blockDim.x + threadIdx.x;
    int row = tid >> 5;
    if (row >= N_NODES) return;
    const int ll  = tid & 31;
    const int j   = ll >> 2;     // edge slot 0..7
    const int seg = ll & 3;      // 8-dim segment 0..3
    const int s = row_ptr[row];
    const int e = row_ptr[row + 1];

    float acc[8];
    #pragma unroll
    for (int k = 0; k < 8; ++k) acc[k] = 0.f;

    for (int i = s; i < e; i += 16) {
        int ea = i + j;
        int eb = i + 8 + j;
        long long pa = (ea < e) ? csr[ea] : 0LL;
        long long pb = (eb < e) ? csr[eb] : 0LL;
        const uint4* qa = (const uint4*)(xin + ((unsigned)pa) * DIM) + seg;
        const uint4* qb = (const uint4*)(xin + ((unsigned)pb) * DIM) + seg;
        uint4 va = *qa;
        uint4 vb = *qb;
        float wa = __int_as_float((int)(pa >> 32));
        float wb = __int_as_float((int)(pb >> 32));
        acc[0] += wa * bflo(va.x); acc[1] += wa * bfhi(va.x);
        acc[2] += wa * bflo(va.y); acc[3] += wa * bfhi(va.y);
        acc[4] += wa * bflo(va.z); acc[5] += wa * bfhi(va.z);
        acc[6] += wa * bflo(va.w); acc[7] += wa * bfhi(va.w);
        acc[0] += wb * bflo(vb.x); acc[1] += wb * bfhi(vb.x);
        acc[2] += wb * bflo(vb.y); acc[3] += wb * bfhi(vb.y);
        acc[4] += wb * bflo(vb.z); acc[5] += wb * bfhi(vb.z);
        acc[6] += wb * bflo(vb.w); acc[7] += wb * bfhi(vb.w);
    }

    // butterfly allreduce over edge slots (lanes stride 4 within half-wave)
    #pragma unroll
    for (int m = 4; m <= 16; m <<= 1) {
        #pragma unroll
        for (int k = 0; k < 8; ++k) acc[k] += __shfl_xor(acc[k], m, 64);
    }

    if (j == 0) {
        int o = row * DIM + seg * 8;           // element offset
        float4* es = (float4*)(emb_sum + o);
        float4 t0 = es[0], t1 = es[1];
        t0.x += acc[0]; t0.y += acc[1]; t0.z += acc[2]; t0.w += acc[3];
        t1.x += acc[4]; t1.y += acc[5]; t1.z += acc[6]; t1.w += acc[7];
        es[0] = t0; es[1] = t1;
        if (write_x) {
            uint4 h;
            h.x = (unsigned)f2bf(acc[0]) | ((unsigned)f2bf(acc[1]) << 16);
            h.y = (unsigned)f2bf(acc[2]) | ((unsigned)f2bf(acc[3]) << 16);
            h.z = (unsigned)f2bf(acc[4]) | ((unsigned)f2bf(acc[5]) << 16);
            h.w = (unsigned)f2bf(acc[6]) | ((unsigned)f2bf(acc[7]) << 16);
            *(uint4*)(xout + o) = h;
        }
    }
}

// ---------------------------------------------------------------------------
// Readout.
// ---------------------------------------------------------------------------
__global__ void final_kernel(const int* __restrict__ users,
                             const int* __restrict__ items,
                             const float* __restrict__ emb_sum,
                             const float* __restrict__ means,
                             const float* __restrict__ stds,
                             float* __restrict__ out) {
    int b = blockIdx.x * blockDim.x + threadIdx.x;
    if (b >= B_OUT) return;
    int u  = users[b];
    int it = items[b] + N_USERS;
    const float4* su = (const float4*)(emb_sum + (size_t)u  * DIM);
    const float4* si = (const float4*)(emb_sum + (size_t)it * DIM);
    float gamma = 0.f;
    #pragma unroll
    for (int k = 0; k < DIM / 4; ++k) {
        float4 a = su[k], c = si[k];
        gamma += (a.x * 0.25f) * (c.x * 0.25f) + (a.y * 0.25f) * (c.y * 0.25f)
               + (a.z * 0.25f) * (c.z * 0.25f) + (a.w * 0.25f) * (c.w * 0.25f);
    }
    out[b] = gamma * stds[u] + means[u];
}

extern "C" void kernel_launch(void* const* d_in, const int* in_sizes, int n_in,
                              void* d_out, int out_size, void* d_ws, size_t ws_size,
                              hipStream_t stream) {
    const int*   users    = (const int*)d_in[0];
    const int*   items    = (const int*)d_in[1];
    const int*   rows     = (const int*)d_in[2];
    const int*   cols     = (const int*)d_in[3];
    const float* vals     = (const float*)d_in[4];
    const float* user_emb = (const float*)d_in[5];
    const float* item_emb = (const float*)d_in[6];
    const float* means    = (const float*)d_in[7];
    const float* stds     = (const float*)d_in[8];
    float* out = (float*)d_out;

    char* w = (char*)d_ws;
    size_t off = 0;
    auto alloc = [&](size_t bytes) -> void* {
        void* p = w + off;
        off = (off + bytes + 255) & ~(size_t)255;
        return p;
    };
    // Region A: bucket_ev (live: part -> mini_scatter) aliases
    //           {x_a, x_b, emb_sum} (live: init -> end).
    size_t regionA = ((size_t)N_PBLK * CH * sizeof(int2) + 255) & ~(size_t)255;  // 64.1 MB
    char* a0 = (char*)alloc(regionA);
    int2* bucket_ev = (int2*)a0;
    size_t aoff = 0;
    auto allocA = [&](size_t bytes) -> void* {
        void* p = a0 + aoff;
        aoff = (aoff + bytes + 255) & ~(size_t)255;
        return p;
    };
    unsigned short* x_a     = (unsigned short*)allocA((size_t)N_NODES * DIM * 2);  // 9.6 MB
    unsigned short* x_b     = (unsigned short*)allocA((size_t)N_NODES * DIM * 2);  // 9.6 MB
    float*          emb_sum = (float*)allocA((size_t)N_NODES * DIM * 4);           // 19.2 MB

    int*  runstart = (int*) alloc((size_t)N_PBLK * RS_LD * sizeof(int));       // 2.0 MB
    int*  partial  = (int*) alloc((size_t)NRED * NB * sizeof(int));
    int*  row_ptr  = (int*) alloc((size_t)(N_NODES + 1) * sizeof(int));
    int*  bcsr     = (int*) alloc((size_t)NB * sizeof(int));
    int2* csr_ev   = (int2*)alloc((size_t)N_EDGES * sizeof(int2));              // 64 MB
    const long long* csr = (const long long*)csr_ev;
    (void)ws_size;

    const int g_init  = (N_NODES * DIM / 4 + T - 1) / T;
    const int g_spmm  = (N_NODES * DIM + T - 1) / T;     // 18750
    const int g_final = (B_OUT + T - 1) / T;

    // --- CSR build ---
    part_kernel<<<N_PBLK, PART_T, 0, stream>>>(rows, cols, vals, runstart, bucket_ev);
    btot_kernel<<<NRED, NB, 0, stream>>>(runstart, partial);
    bscan_kernel<<<1, NB, 0, stream>>>(partial, bcsr, row_ptr);
    mini_scatter_kernel<<<NB, MS_T, 0, stream>>>(runstart, bucket_ev, bcsr, row_ptr, csr_ev);

    // --- dense pipeline (bucket_ev dead from here; region reused) ---
    init_kernel<<<g_init, T, 0, stream>>>(user_emb, item_emb, x_a, emb_sum);
    spmm_kernel<<<g_spmm, T, 0, stream>>>(row_ptr, csr, x_a, x_b, emb_sum, 1);
    spmm_kernel<<<g_spmm, T, 0, stream>>>(row_ptr, csr, x_b, x_a, emb_sum, 1);
    spmm_kernel<<<g_spmm, T, 0, stream>>>(row_ptr, csr, x_a, x_b, emb_sum, 0);

    final_kernel<<<g_final, T, 0, stream>>>(users, items, emb_sum, means, stds, out);
}